// Round 3
// baseline (240.386 us; speedup 1.0000x reference)
//
#include <hip/hip_runtime.h>

// SparseGlobalBroadcast: out[n][c] = in_feat[n][c] + glob_feat[batch_idx[n]][c]
// N = 1e6, C = 128, B = 8, fp32. Memory-bound streaming gather-add.
// R2: same as R1 but with native clang vector type (ext_vector_type) so the
//     nontemporal builtins compile (HIP float4 is a struct -> rejected).

#define SGB_C   128
#define SGB_C4  (SGB_C / 4)   // 32 f32x4 per row -> row = idx >> 5

typedef float f32x4 __attribute__((ext_vector_type(4)));

__global__ __launch_bounds__(256) void SparseGlobalBroadcast_27762668601803_kernel(
    const f32x4* __restrict__ in4,
    const f32x4* __restrict__ glob4,    // B * C4 vectors (256 total)
    const int*   __restrict__ bidx,
    f32x4*       __restrict__ out4,
    int n4,                             // N * C/4 total f32x4 elements
    int b_times_c4)                     // B * C4 (256)
{
    __shared__ f32x4 g_lds[8 * SGB_C4];   // 4 KB (B=8)

    const int t = threadIdx.x;
    if (t < b_times_c4) g_lds[t] = glob4[t];
    __syncthreads();

    const int stride  = gridDim.x * blockDim.x;
    const int stride4 = stride * 4;
    int i = blockIdx.x * blockDim.x + t;

    // Main loop: 4 independent strided f32x4 elements per iteration.
    for (; i + 3 * stride < n4; i += stride4) {
        const int i0 = i;
        const int i1 = i + stride;
        const int i2 = i + 2 * stride;
        const int i3 = i + 3 * stride;

        // Issue all 4 streamed loads first (4-deep MLP), nt hint (no reuse).
        f32x4 a0 = __builtin_nontemporal_load(&in4[i0]);
        f32x4 a1 = __builtin_nontemporal_load(&in4[i1]);
        f32x4 a2 = __builtin_nontemporal_load(&in4[i2]);
        f32x4 a3 = __builtin_nontemporal_load(&in4[i3]);

        const int b0 = bidx[i0 >> 5];
        const int b1 = bidx[i1 >> 5];
        const int b2 = bidx[i2 >> 5];
        const int b3 = bidx[i3 >> 5];

        a0 += g_lds[b0 * SGB_C4 + (i0 & (SGB_C4 - 1))];
        a1 += g_lds[b1 * SGB_C4 + (i1 & (SGB_C4 - 1))];
        a2 += g_lds[b2 * SGB_C4 + (i2 & (SGB_C4 - 1))];
        a3 += g_lds[b3 * SGB_C4 + (i3 & (SGB_C4 - 1))];

        __builtin_nontemporal_store(a0, &out4[i0]);
        __builtin_nontemporal_store(a1, &out4[i1]);
        __builtin_nontemporal_store(a2, &out4[i2]);
        __builtin_nontemporal_store(a3, &out4[i3]);
    }

    // Tail: remaining strided singles.
    for (; i < n4; i += stride) {
        const int b = bidx[i >> 5];
        f32x4 a = __builtin_nontemporal_load(&in4[i]);
        a += g_lds[b * SGB_C4 + (i & (SGB_C4 - 1))];
        __builtin_nontemporal_store(a, &out4[i]);
    }
}

extern "C" void kernel_launch(void* const* d_in, const int* in_sizes, int n_in,
                              void* d_out, int out_size, void* d_ws, size_t ws_size,
                              hipStream_t stream) {
    const f32x4* in4   = (const f32x4*)d_in[0];   // in_feat  [N, C] fp32
    const f32x4* glob4 = (const f32x4*)d_in[1];   // glob_feat [B, C] fp32
    const int*   bidx  = (const int*)d_in[2];     // batch_idx [N] int32
    f32x4*       out4  = (f32x4*)d_out;

    const int N  = in_sizes[2];                 // 1,000,000
    const int n4 = N * SGB_C4;                  // 32,000,000 f32x4 elements
    const int b_times_c4 = in_sizes[1] / 4;     // B * C4 = 256

    const int block = 256;
    int grid = (n4 + block - 1) / block;
    if (grid > 2048) grid = 2048;               // grid-stride the rest

    SparseGlobalBroadcast_27762668601803_kernel<<<grid, block, 0, stream>>>(
        in4, glob4, bidx, out4, n4, b_times_c4);
}